// Round 4
// baseline (210.635 us; speedup 1.0000x reference)
//
#include <hip/hip_runtime.h>
#include <math.h>

// x:     [4, 3, 1024, 1024] f32
// param: [4, 72, 256, 256]  f32 ; channel ch = c*24 + i*8 + z = (3c+i)*8 + z
// out:   [4, 3, 1024, 1024] f32 = tanh(sum_i trilinear(curve))
//
// Single fused kernel. Per 64x4 pixel tile, the needed param footprint is
// 3 rows x 18 cells x 72 ch. Staged global->LDS with channel reorder into
// [cell][(i*8+z)*4 + c] (z-slot padded to 4 dw, 16B aligned) so the inner
// loop fetches all 3 output channels of one z-plane with ONE ds_read_b128.
// Cell stride 100 dw (=4 mod 32) + z in the start bank spreads b128 reads
// across all 32 banks.
#define IMG 1024
#define HW (IMG * IMG)
#define TS 256
#define CH_STRIDE (TS * TS)
#define PARAM_B_STRIDE (72 * CH_STRIDE)
#define S_CONST (255.0f / 1023.0f)

#define TILE_W 64
#define TILE_H 4
#define ROWS 3            // y-span of 4-row tile incl. y1
#define CELLS 18          // x-span of 64-col tile incl. x1
#define CELL_F4 25        // 100 dwords per cell (96 used + 4 pad)
#define ROW_F4S (CELLS * CELL_F4)   // 450 float4 per row

__global__ __launch_bounds__(256) void curve3d_fused(
    const float* __restrict__ x, const float* __restrict__ param,
    float* __restrict__ out)
{
    __shared__ float4 sh[ROWS * ROW_F4S];   // 21600 B
    float* shf = (float*)sh;

    int blk = blockIdx.x;                   // b*4096 + ht*16 + wt
    int wt = blk & 15;
    int ht = (blk >> 4) & 255;
    int b  = blk >> 12;
    int tid = threadIdx.x;

    int w0 = wt * TILE_W, h0 = ht * TILE_H;
    int xb = (int)((float)w0 * S_CONST);    // base cell; x0 in [xb, xb+16]
    int yb = (int)((float)h0 * S_CONST);    // base row;  y0 in [yb, yb+1]

    // ---- staging: 216 threads cover 12 ch-slots x 18 cells; 6 reps over ch
    if (tid < 216) {
        int q  = tid / 18;                  // 0..11
        int xx = tid - q * 18;              // 0..17  (= cell index)
        int xs = min(xb + xx, 255);         // border clamp (also avoids OOB)
        const float* pb = param + (size_t)b * PARAM_B_STRIDE + xs;
        const float* p0 = pb + min(yb + 0, 255) * TS;
        const float* p1 = pb + min(yb + 1, 255) * TS;
        const float* p2 = pb + min(yb + 2, 255) * TS;
        float* d = shf + xx * 100;
#pragma unroll
        for (int rep = 0; rep < 6; ++rep) {
            int ch = q + 12 * rep;          // 0..71, each exactly once
            int z  = ch & 7;
            int m  = ch >> 3;               // 0..8 = 3c + i
            int cc = (m * 11) >> 5;         // m/3
            int ii = m - cc * 3;
            int off = ((ii << 3) + z) * 4 + cc;
            size_t go = (size_t)ch * CH_STRIDE;
            d[off]          = p0[go];
            d[1800 + off]   = p1[go];
            d[3600 + off]   = p2[go];
        }
    }
    __syncthreads();

    // ---- compute: one pixel per thread
    int tw = tid & 63, th = tid >> 6;
    int w = w0 + tw, h = h0 + th;

    float ix = (float)w * S_CONST; int x0 = (int)ix; float wx = ix - (float)x0;
    float iy = (float)h * S_CONST; int y0 = (int)iy; float wy = iy - (float)y0;
    int c0 = x0 - xb;
    int c1 = min(x0 + 1, 255) - xb;
    int r0 = y0 - yb;
    int r1 = min(y0 + 1, 255) - yb;

    const float* xp = x + (size_t)b * 3 * HW + (size_t)h * IMG + w;
    int zi[3]; float wz[3];
#pragma unroll
    for (int i = 0; i < 3; ++i) {
        float xv = xp[(size_t)i * HW];
        float izf = fminf(fmaxf(fmaf(xv, 3.5f, 3.5f), 0.0f), 7.0f);
        int z = min((int)izf, 6);
        zi[i] = z;
        wz[i] = izf - (float)z;
    }

    float u0 = 1.0f - wx, v0 = 1.0f - wy;
    float wcs[4] = {v0 * u0, v0 * wx, wy * u0, wy * wx};
    const float4* cell[4] = {
        sh + r0 * ROW_F4S + c0 * CELL_F4,
        sh + r0 * ROW_F4S + c1 * CELL_F4,
        sh + r1 * ROW_F4S + c0 * CELL_F4,
        sh + r1 * ROW_F4S + c1 * CELL_F4
    };

    float acc0 = 0.0f, acc1 = 0.0f, acc2 = 0.0f;
#pragma unroll
    for (int i = 0; i < 3; ++i) {
        int o = (i << 3) + zi[i];           // f4 slot: z-plane, all 3 c's
        float wzi = wz[i];
#pragma unroll
        for (int k = 0; k < 4; ++k) {
            float4 a = cell[k][o];          // ds_read_b128: c0,c1,c2 @ z
            float4 bv = cell[k][o + 1];     // ds_read_b128: c0,c1,c2 @ z+1
            float wb = wcs[k] * wzi;
            float wa = wcs[k] - wb;
            acc0 = fmaf(a.x, wa, fmaf(bv.x, wb, acc0));
            acc1 = fmaf(a.y, wa, fmaf(bv.y, wb, acc1));
            acc2 = fmaf(a.z, wa, fmaf(bv.z, wb, acc2));
        }
    }

    float* op = out + (size_t)b * 3 * HW + (size_t)h * IMG + w;
    float e0 = __expf(2.0f * acc0);
    float e1 = __expf(2.0f * acc1);
    float e2 = __expf(2.0f * acc2);
    op[0]            = 1.0f - 2.0f / (e0 + 1.0f);
    op[(size_t)HW]   = 1.0f - 2.0f / (e1 + 1.0f);
    op[(size_t)2*HW] = 1.0f - 2.0f / (e2 + 1.0f);
}

extern "C" void kernel_launch(void* const* d_in, const int* in_sizes, int n_in,
                              void* d_out, int out_size, void* d_ws, size_t ws_size,
                              hipStream_t stream) {
    const float* x = (const float*)d_in[0];
    const float* param = (const float*)d_in[1];
    float* out = (float*)d_out;
    // blocks: 16 w-tiles * 256 h-tiles * 4 batches
    curve3d_fused<<<dim3(16 * 256 * 4), dim3(256), 0, stream>>>(x, param, out);
}

// Round 5
// 185.146 us; speedup vs baseline: 1.1377x; 1.1377x over previous
//
#include <hip/hip_runtime.h>
#include <math.h>

// x:     [4, 3, 1024, 1024] f32
// param: [4, 72, 256, 256]  f32 ; channel ch = c*24 + i*8 + z = (3c+i)*8 + z
// out:   [4, 3, 1024, 1024] f32 = tanh(sum_i trilinear(curve))
//
// Single fused kernel, 256x4 pixel tile per 1024-thread block.
// Footprint: 3 rows x 66 cells x 72 ch staged to LDS.
//  - global reads: per (ch,row) a contiguous 66-dw run -> 64-lane coalesced
//  - LDS cell stride 77 dw (%32 = 13, odd) -> staging writes exactly 2
//    lanes/bank (free); compute reads spread over all banks even though
//    the data-dependent z only takes values {3,4,5,6} for this input dist.
#define IMG 1024
#define HW (IMG * IMG)
#define TS 256
#define CH_STRIDE (TS * TS)
#define PARAM_B_STRIDE (72 * CH_STRIDE)
#define S_CONST (255.0f / 1023.0f)

#define ROWS 3
#define CELLS 66
#define CELL_DW 77                  // 72 + 5 pad
#define ROW_DW (CELLS * CELL_DW)    // 5082
#define LDS_DW (ROWS * ROW_DW)      // 15246 dw = 60984 B

__global__ __launch_bounds__(1024, 8) void curve3d_fused(
    const float* __restrict__ x, const float* __restrict__ param,
    float* __restrict__ out)
{
    __shared__ float sh[LDS_DW];
    int blk = blockIdx.x;                 // b*1024 + ht*4 + wt
    int wt = blk & 3;
    int ht = (blk >> 2) & 255;
    int b  = blk >> 10;
    int tid = threadIdx.x;

    int w0 = wt * 256, h0 = ht * 4;
    int xb = (int)((float)w0 * S_CONST);  // base cell; cells xb..xb+65 cover tile
    int yb = (int)((float)h0 * S_CONST);  // base row; rows yb..yb+2

    // ---- pixel mapping + x loads early (independent of LDS) ----
    int tw = tid & 255, th = tid >> 8;
    int w = w0 + tw, h = h0 + th;
    const float* xp = x + (size_t)b * 3 * HW + (size_t)h * IMG + w;
    float xv[3];
    xv[0] = xp[0]; xv[1] = xp[(size_t)HW]; xv[2] = xp[(size_t)2 * HW];

    // ---- staging: 216 runs (row,ch) x 66 dw; main 64 dw per run by one wave
    int g = tid >> 6, u = tid & 63;
    const float* pb = param + (size_t)b * PARAM_B_STRIDE;
    int ys0 = min(yb, 255), ys1 = min(yb + 1, 255), ys2 = min(yb + 2, 255);
#pragma unroll
    for (int j = 0; j < 14; ++j) {
        int rid = j * 16 + g;             // run id in [0,224); 216 used
        if (rid < 216) {
            int row = (rid >= 144) ? 2 : ((rid >= 72) ? 1 : 0);
            int ch = rid - row * 72;
            int ys = (row == 2) ? ys2 : ((row == 1) ? ys1 : ys0);
            // xb+u <= 191+63 = 254 < 255: no clamp needed for main run
            float v = pb[(size_t)ch * CH_STRIDE + ys * TS + (xb + u)];
            sh[row * ROW_DW + u * CELL_DW + ch] = v;
        }
    }
    // tail cells xx = 64, 65 (432 loads; border clamp applies here)
    if (tid < 432) {
        int rid = tid >> 1;
        int xx = 64 + (tid & 1);
        int row = (rid >= 144) ? 2 : ((rid >= 72) ? 1 : 0);
        int ch = rid - row * 72;
        int ys = (row == 2) ? ys2 : ((row == 1) ? ys1 : ys0);
        int xs = min(xb + xx, 255);
        sh[row * ROW_DW + xx * CELL_DW + ch] =
            pb[(size_t)ch * CH_STRIDE + ys * TS + xs];
    }

    // ---- z prep (no LDS dependence, before barrier) ----
    int zi[3]; float wz[3];
#pragma unroll
    for (int i = 0; i < 3; ++i) {
        float izf = fminf(fmaxf(fmaf(xv[i], 3.5f, 3.5f), 0.0f), 7.0f);
        int z = min((int)izf, 6);
        zi[i] = z;
        wz[i] = izf - (float)z;
    }

    __syncthreads();

    // ---- compute: one pixel per thread ----
    float ix = (float)w * S_CONST; int x0 = (int)ix; float wx = ix - (float)x0;
    float iy = (float)h * S_CONST; int y0 = (int)iy; float wy = iy - (float)y0;
    int c0 = x0 - xb;
    int c1 = min(x0 + 1, 255) - xb;
    int r0 = y0 - yb;
    int r1 = min(y0 + 1, 255) - yb;

    float u0 = 1.0f - wx, v0 = 1.0f - wy;
    float wcs[4] = {v0 * u0, v0 * wx, wy * u0, wy * wx};
    const float* bases[4] = {
        sh + r0 * ROW_DW + c0 * CELL_DW,
        sh + r0 * ROW_DW + c1 * CELL_DW,
        sh + r1 * ROW_DW + c0 * CELL_DW,
        sh + r1 * ROW_DW + c1 * CELL_DW
    };

    float* op = out + (size_t)b * 3 * HW + (size_t)h * IMG + w;
#pragma unroll
    for (int c = 0; c < 3; ++c) {
        float acc = 0.0f;
#pragma unroll
        for (int i = 0; i < 3; ++i) {
            int off = (c * 3 + i) * 8 + zi[i];
            float wzi = wz[i];
#pragma unroll
            for (int k = 0; k < 4; ++k) {
                float2 v;
                __builtin_memcpy(&v, bases[k] + off, 8);  // ds_read2_b32
                float wb = wcs[k] * wzi;
                float wa = wcs[k] - wb;
                acc = fmaf(v.x, wa, fmaf(v.y, wb, acc));
            }
        }
        float e = __expf(2.0f * acc);
        op[(size_t)c * HW] = 1.0f - 2.0f / (e + 1.0f);
    }
}

extern "C" void kernel_launch(void* const* d_in, const int* in_sizes, int n_in,
                              void* d_out, int out_size, void* d_ws, size_t ws_size,
                              hipStream_t stream) {
    const float* x = (const float*)d_in[0];
    const float* param = (const float*)d_in[1];
    float* out = (float*)d_out;
    // blocks: 4 batches * 256 h-tiles * 4 w-tiles
    curve3d_fused<<<dim3(4 * 256 * 4), dim3(1024), 0, stream>>>(x, param, out);
}